// Round 10
// baseline (123.443 us; speedup 1.0000x reference)
//
#include <hip/hip_runtime.h>

#define NCLS 20
#define IGNORE_INDEX (-1)
#define TPB 1024
#define PAIRS_PER_THREAD 8
#define PPB (TPB * PAIRS_PER_THREAD)   // 8192 pairs per block
#define HASH_WORDS 16384               // 262144 points * 2 bits / 32

__device__ __forceinline__ void softmax_row(const float* __restrict__ row, float* v) {
    const float4* r4 = (const float4*)row;   // 80B rows, 16B-aligned
#pragma unroll
    for (int q = 0; q < 5; ++q) {
        float4 t = r4[q];
        v[4 * q + 0] = t.x; v[4 * q + 1] = t.y;
        v[4 * q + 2] = t.z; v[4 * q + 3] = t.w;
    }
    float mx = v[0];
#pragma unroll
    for (int c = 1; c < NCLS; ++c) mx = fmaxf(mx, v[c]);
    float s = 0.f;
#pragma unroll
    for (int c = 0; c < NCLS; ++c) { v[c] = __expf(v[c] - mx); s += v[c]; }
    float inv = 1.0f / s;
#pragma unroll
    for (int c = 0; c < NCLS; ++c) v[c] *= inv;
}

// ---- prep: pack (label & 3) for 16 points per uint32 (coalesced) -----------
__global__ __launch_bounds__(256) void hash_prep(const int* __restrict__ labels,
                                                 unsigned int* __restrict__ H,
                                                 int words) {
    int w = blockIdx.x * blockDim.x + threadIdx.x;
    if (w >= words) return;
    const int4* lp = (const int4*)(labels + (size_t)w * 16);
    int4 v0 = lp[0], v1 = lp[1], v2 = lp[2], v3 = lp[3];
    int l[16] = {v0.x, v0.y, v0.z, v0.w, v1.x, v1.y, v1.z, v1.w,
                 v2.x, v2.y, v2.z, v2.w, v3.x, v3.y, v3.z, v3.w};
    unsigned int acc = 0;
#pragma unroll
    for (int k = 0; k < 16; ++k)
        acc |= ((unsigned int)(l[k] & 3)) << (2 * k);
    H[w] = acc;
}

// ---- fused: LDS hash filter -> verify gather -> row gathers + distance -----
// 64 KB LDS table => 2 blocks/CU x 1024 thr = 32 waves/CU (full occupancy).
// Request budget: ~1.05M verify gathers (hash FP rate 0.2) + 2.1M row float4s
// vs 6.3M without the filter. No compaction: divergent VALU is free (4-8%
// busy); only divergent memory requests cost (~3.4 cyc each, R9 analysis).
__global__ __launch_bounds__(TPB) void fused_kernel(
    const float* __restrict__ logits, const int* __restrict__ labels,
    const int* __restrict__ ref_idx, const unsigned int* __restrict__ H,
    unsigned int* __restrict__ counts, float* __restrict__ partials,
    long long total_pairs) {
    __shared__ unsigned int s_hash[HASH_WORDS];  // 64 KB exactly; tail aliased later
    const int tid = threadIdx.x;

    // coalesced table load: 4096 uint4 / 1024 threads = 4 each
    {
        const uint4* src = (const uint4*)H;
        uint4* dst = (uint4*)s_hash;
#pragma unroll
        for (int i = 0; i < 4; ++i) dst[tid + i * TPB] = src[tid + i * TPB];
    }
    __syncthreads();

    float fsum = 0.f;
    unsigned int cnt = 0;
    const long long pair0 = (long long)blockIdx.x * PPB +
                            (long long)tid * PAIRS_PER_THREAD;
    if (pair0 + PAIRS_PER_THREAD <= total_pairs) {
        const int p = (int)(pair0 >> 4);        // 8 | 16: one center per thread
        const int li = labels[p];               // lanes 2t,2t+1 share -> coalesced
        int4 ra = *(const int4*)(ref_idx + pair0);
        int4 rb = *(const int4*)(ref_idx + pair0 + 4);
        int rr[8] = {ra.x, ra.y, ra.z, ra.w, rb.x, rb.y, rb.z, rb.w};
        if (li != IGNORE_INDEX) {
            const unsigned int h_li = (unsigned int)(li & 3);
            unsigned int hv[8];
#pragma unroll
            for (int j = 0; j < 8; ++j) {       // 8 independent LDS lookups
                int idx = max(rr[j], 0);
                hv[j] = (s_hash[idx >> 4] >> (2 * (idx & 15))) & 3u;
            }
#pragma unroll
            for (int j = 0; j < 8; ++j) {
                if (rr[j] >= 0 && hv[j] == h_li) {      // ~25% of pairs
                    int nl = labels[rr[j]];             // global verify gather
                    if (nl == li) {                     // ~5% of pairs
                        float a[NCLS], b[NCLS];
                        softmax_row(logits + (size_t)p * NCLS, a);
                        softmax_row(logits + (size_t)rr[j] * NCLS, b);
                        float d = 0.f;
#pragma unroll
                        for (int k = 0; k < NCLS; ++k) {
                            float dx = a[k] - b[k];
                            d = fmaf(dx, dx, d);
                        }
                        fsum += d;
                        cnt += 1u;
                    }
                }
            }
        }
    }

    // ---- block reduction: wave shuffle, then LDS (aliased into s_hash) -----
#pragma unroll
    for (int off = 32; off > 0; off >>= 1) {
        fsum += __shfl_down(fsum, off, 64);
        cnt  += __shfl_down(cnt,  off, 64);
    }
    __syncthreads();                       // all hash reads done before aliasing
    float* s_f        = (float*)s_hash;          // [0..15]
    unsigned int* s_c = s_hash + 64;             // [64..79]
    if ((tid & 63) == 0) { s_f[tid >> 6] = fsum; s_c[tid >> 6] = cnt; }
    __syncthreads();
    if (tid == 0) {
        float ts = 0.f; unsigned int tc = 0;
#pragma unroll
        for (int w = 0; w < TPB / 64; ++w) { ts += s_f[w]; tc += s_c[w]; }
        partials[blockIdx.x] = ts;
        counts[blockIdx.x] = tc;
    }
}

// ---- final single-block reduction ------------------------------------------
__global__ __launch_bounds__(1024) void reduce_kernel(
    const float* __restrict__ partials, const unsigned int* __restrict__ counts,
    float* __restrict__ out, int m) {
    double dsum = 0.0;
    unsigned long long cnt = 0;
    for (int i = threadIdx.x; i < m; i += 1024) {
        dsum += (double)partials[i];
        // clamp: counts may be 0xAA-poisoned in an isolated rocprof replay
        cnt  += (unsigned long long)min(counts[i], (unsigned int)PPB);
    }
#pragma unroll
    for (int off = 32; off > 0; off >>= 1) {
        dsum += __shfl_down(dsum, off, 64);
        cnt  += __shfl_down(cnt,  off, 64);
    }
    __shared__ double s_sum[16];
    __shared__ unsigned long long s_cnt[16];
    const int wave = threadIdx.x >> 6;
    if ((threadIdx.x & 63) == 0) { s_sum[wave] = dsum; s_cnt[wave] = cnt; }
    __syncthreads();
    if (threadIdx.x == 0) {
        double ts = 0.0; unsigned long long tc = 0;
        for (int w = 0; w < 16; ++w) { ts += s_sum[w]; tc += s_cnt[w]; }
        if (tc < 1ull) tc = 1ull;
        out[0] = (float)(ts / (double)tc);     // LOSS_WEIGHT = 1.0
    }
}

extern "C" void kernel_launch(void* const* d_in, const int* in_sizes, int n_in,
                              void* d_out, int out_size, void* d_ws, size_t ws_size,
                              hipStream_t stream) {
    const float* seg_logits = (const float*)d_in[0];
    // d_in[1] = coord — unused (KNN indices are given)
    const int* labels  = (const int*)d_in[2];
    const int* ref_idx = (const int*)d_in[3];
    float* out = (float*)d_out;
    const int n = in_sizes[2];                       // 262144
    const long long total_pairs = (long long)n * 16; // 4,194,304
    const int blocks = (int)((total_pairs + PPB - 1) / PPB);   // 512

    // ws layout: H[16384] (64 KB) | counts[512] | partials[512]
    unsigned int* H        = (unsigned int*)d_ws;
    unsigned int* counts   = (unsigned int*)((char*)d_ws + HASH_WORDS * 4);
    float* partials        = (float*)((char*)d_ws + HASH_WORDS * 4 + 512 * 4);

    hash_prep<<<(HASH_WORDS + 255) / 256, 256, 0, stream>>>(labels, H, HASH_WORDS);
    fused_kernel<<<blocks, TPB, 0, stream>>>(seg_logits, labels, ref_idx, H,
                                             counts, partials, total_pairs);
    reduce_kernel<<<1, 1024, 0, stream>>>(partials, counts, out, blocks);
}

// Round 11
// 118.754 us; speedup vs baseline: 1.0395x; 1.0395x over previous
//
#include <hip/hip_runtime.h>

#define NCLS 20
#define IGNORE_INDEX (-1)
#define TPB 1024
#define PAIRS_PER_THREAD 8
#define PPB (TPB * PAIRS_PER_THREAD)   // 8192 pairs per block -> 512 blocks
#define HASH_WORDS 16384               // 64 KB: 2-bit hash for 262144 points
#define BUFCAP 1024                    // expected hash-pass survivors/block ~418
#define RBITS 18                       // n = 2^18

__device__ __forceinline__ void softmax_row(const float* __restrict__ row, float* v) {
    const float4* r4 = (const float4*)row;   // 80B rows, 16B-aligned
#pragma unroll
    for (int q = 0; q < 5; ++q) {
        float4 t = r4[q];
        v[4 * q + 0] = t.x; v[4 * q + 1] = t.y;
        v[4 * q + 2] = t.z; v[4 * q + 3] = t.w;
    }
    float mx = v[0];
#pragma unroll
    for (int c = 1; c < NCLS; ++c) mx = fmaxf(mx, v[c]);
    float s = 0.f;
#pragma unroll
    for (int c = 0; c < NCLS; ++c) { v[c] = __expf(v[c] - mx); s += v[c]; }
    float inv = 1.0f / s;
#pragma unroll
    for (int c = 0; c < NCLS; ++c) v[c] *= inv;
}

__device__ __forceinline__ float pair_dist(const float* __restrict__ logits,
                                           int p, int r) {
    float a[NCLS], b[NCLS];
    softmax_row(logits + (size_t)p * NCLS, a);
    softmax_row(logits + (size_t)r * NCLS, b);
    float d = 0.f;
#pragma unroll
    for (int k = 0; k < NCLS; ++k) {
        float dx = a[k] - b[k];
        d = fmaf(dx, dx, d);
    }
    return d;
}

// ---- prep: pack (label & 3) for 16 points per uint32 (coalesced) -----------
__global__ __launch_bounds__(256) void hash_prep(const int* __restrict__ labels,
                                                 unsigned int* __restrict__ H,
                                                 int words) {
    int w = blockIdx.x * blockDim.x + threadIdx.x;
    if (w >= words) return;
    const int4* lp = (const int4*)(labels + (size_t)w * 16);
    int4 v0 = lp[0], v1 = lp[1], v2 = lp[2], v3 = lp[3];
    int l[16] = {v0.x, v0.y, v0.z, v0.w, v1.x, v1.y, v1.z, v1.w,
                 v2.x, v2.y, v2.z, v2.w, v3.x, v3.y, v3.z, v3.w};
    unsigned int acc = 0;
#pragma unroll
    for (int k = 0; k < 16; ++k)
        acc |= ((unsigned int)(l[k] & 3)) << (2 * k);
    H[w] = acc;
}

// Fused: phase 1 = LDS-hash filter (ZERO divergent global requests) + LDS
// compaction of hash-passers; phase 2 = ONE lane-dense round: verify gather +
// row gathers + distance. R10 lesson: wave-level body issue is what costs —
// compaction keeps the ~300-inst body at ~1 issue/wave instead of 8.
__global__ __launch_bounds__(TPB) void fused_kernel(
    const float* __restrict__ logits, const int* __restrict__ labels,
    const int* __restrict__ ref_idx, const unsigned int* __restrict__ H,
    unsigned int* __restrict__ counts, float* __restrict__ partials,
    long long total_pairs) {
    __shared__ unsigned int s_hash[HASH_WORDS];   // 64 KB
    __shared__ uint2 s_buf[BUFCAP];               // 8 KB: {(li<<RBITS)|r, p}
    __shared__ int s_cnt;
    __shared__ float s_wsum[TPB / 64];
    __shared__ unsigned int s_wcnt[TPB / 64];
    const int tid = threadIdx.x;
    if (tid == 0) s_cnt = 0;

    // coalesced hash-table load: 4096 uint4 / 1024 threads
    {
        const uint4* src = (const uint4*)H;
        uint4* dst = (uint4*)s_hash;
#pragma unroll
        for (int i = 0; i < 4; ++i) dst[tid + i * TPB] = src[tid + i * TPB];
    }
    __syncthreads();

    float fsum = 0.f;
    unsigned int cnt = 0;

    // ---- phase 1: hash filter + compaction (no divergent global loads) -----
    const long long pair0 = (long long)blockIdx.x * PPB +
                            (long long)tid * PAIRS_PER_THREAD;
    if (pair0 + PAIRS_PER_THREAD <= total_pairs) {
        const int p = (int)(pair0 >> 4);        // 8 | 16: one center per thread
        const int li = labels[p];               // coalesced (2 lanes share)
        int4 ra = *(const int4*)(ref_idx + pair0);
        int4 rb = *(const int4*)(ref_idx + pair0 + 4);
        int rr[8] = {ra.x, ra.y, ra.z, ra.w, rb.x, rb.y, rb.z, rb.w};
        if (li != IGNORE_INDEX) {
            const unsigned int h_li = (unsigned int)(li & 3);
            unsigned int hv[8];
#pragma unroll
            for (int j = 0; j < 8; ++j) {       // 8 independent LDS lookups
                int idx = max(rr[j], 0);
                hv[j] = (s_hash[idx >> 4] >> (2 * (idx & 15))) & 3u;
            }
#pragma unroll
            for (int j = 0; j < 8; ++j) {
                if (rr[j] >= 0 && hv[j] == h_li) {        // ~25% pass hash
                    int slot = atomicAdd(&s_cnt, 1);      // LDS atomic: cheap
                    if (slot < BUFCAP) {
                        s_buf[slot] = make_uint2(
                            ((unsigned int)li << RBITS) | (unsigned int)rr[j],
                            (unsigned int)p);
                    } else {
                        // overflow slow path (Poisson mean 418, cap 1024:
                        // statistically never; keeps correctness regardless)
                        int nl = labels[rr[j]];
                        if (nl == li) { fsum += pair_dist(logits, p, rr[j]); cnt += 1u; }
                    }
                }
            }
        }
    }
    __syncthreads();
    const int c = min(s_cnt, BUFCAP);

    // ---- phase 2: ONE lane-dense round: verify gather -> rows -> distance --
    for (int i = tid; i < c; i += TPB) {
        uint2 e = s_buf[i];
        int r  = (int)(e.x & ((1u << RBITS) - 1u));
        int li = (int)(e.x >> RBITS);
        int p  = (int)e.y;
        int nl = labels[r];                     // lane-dense verify gather
        if (nl == li) {                         // ~20% of hash-passers
            fsum += pair_dist(logits, p, r);
            cnt += 1u;
        }
    }

    // ---- block reduction -> plain stores (no global atomics) ---------------
#pragma unroll
    for (int off = 32; off > 0; off >>= 1) {
        fsum += __shfl_down(fsum, off, 64);
        cnt  += __shfl_down(cnt,  off, 64);
    }
    if ((tid & 63) == 0) { s_wsum[tid >> 6] = fsum; s_wcnt[tid >> 6] = cnt; }
    __syncthreads();
    if (tid == 0) {
        float ts = 0.f; unsigned int tc = 0;
#pragma unroll
        for (int w = 0; w < TPB / 64; ++w) { ts += s_wsum[w]; tc += s_wcnt[w]; }
        partials[blockIdx.x] = ts;
        counts[blockIdx.x] = tc;
    }
}

// ---- final single-block reduction ------------------------------------------
__global__ __launch_bounds__(1024) void reduce_kernel(
    const float* __restrict__ partials, const unsigned int* __restrict__ counts,
    float* __restrict__ out, int m) {
    double dsum = 0.0;
    unsigned long long cnt = 0;
    for (int i = threadIdx.x; i < m; i += 1024) {
        dsum += (double)partials[i];
        // clamp: counts may be 0xAA-poisoned in an isolated rocprof replay
        cnt  += (unsigned long long)min(counts[i], (unsigned int)PPB);
    }
#pragma unroll
    for (int off = 32; off > 0; off >>= 1) {
        dsum += __shfl_down(dsum, off, 64);
        cnt  += __shfl_down(cnt,  off, 64);
    }
    __shared__ double s_sum[16];
    __shared__ unsigned long long s_cnt[16];
    const int wave = threadIdx.x >> 6;
    if ((threadIdx.x & 63) == 0) { s_sum[wave] = dsum; s_cnt[wave] = cnt; }
    __syncthreads();
    if (threadIdx.x == 0) {
        double ts = 0.0; unsigned long long tc = 0;
        for (int w = 0; w < 16; ++w) { ts += s_sum[w]; tc += s_cnt[w]; }
        if (tc < 1ull) tc = 1ull;
        out[0] = (float)(ts / (double)tc);     // LOSS_WEIGHT = 1.0
    }
}

extern "C" void kernel_launch(void* const* d_in, const int* in_sizes, int n_in,
                              void* d_out, int out_size, void* d_ws, size_t ws_size,
                              hipStream_t stream) {
    const float* seg_logits = (const float*)d_in[0];
    // d_in[1] = coord — unused (KNN indices are given)
    const int* labels  = (const int*)d_in[2];
    const int* ref_idx = (const int*)d_in[3];
    float* out = (float*)d_out;
    const int n = in_sizes[2];                       // 262144
    const long long total_pairs = (long long)n * 16; // 4,194,304
    const int blocks = (int)((total_pairs + PPB - 1) / PPB);   // 512

    // ws layout: H[16384] (64 KB) | counts[512] | partials[512]
    unsigned int* H      = (unsigned int*)d_ws;
    unsigned int* counts = (unsigned int*)((char*)d_ws + HASH_WORDS * 4);
    float* partials      = (float*)((char*)d_ws + HASH_WORDS * 4 + 512 * 4);

    hash_prep<<<(HASH_WORDS + 255) / 256, 256, 0, stream>>>(labels, H, HASH_WORDS);
    fused_kernel<<<blocks, TPB, 0, stream>>>(seg_logits, labels, ref_idx, H,
                                             counts, partials, total_pairs);
    reduce_kernel<<<1, 1024, 0, stream>>>(partials, counts, out, blocks);
}

// Round 13
// 104.948 us; speedup vs baseline: 1.1762x; 1.1315x over previous
//
#include <hip/hip_runtime.h>

#define NCLS 20
#define IGNORE_INDEX (-1)
#define TPB 128             // 2-wave blocks; 16 blocks/CU co-resident
#define PAIRS_PER_THREAD 8
#define PPB (TPB * PAIRS_PER_THREAD)   // 1024 pairs per block
#define BLOCKS 4096                    // 4,194,304 / 1024
#define RBITS 18            // n = 262144 = 2^18 -> neighbor index fits 18 bits

// native clang vector type: __builtin_nontemporal_load rejects HIP_vector_type
typedef int vint4 __attribute__((ext_vector_type(4)));

__device__ __forceinline__ void softmax_row(const float* __restrict__ row, float* v) {
    const float4* r4 = (const float4*)row;   // 80B rows, 16B-aligned
#pragma unroll
    for (int q = 0; q < 5; ++q) {
        float4 t = r4[q];
        v[4 * q + 0] = t.x; v[4 * q + 1] = t.y;
        v[4 * q + 2] = t.z; v[4 * q + 3] = t.w;
    }
    float mx = v[0];
#pragma unroll
    for (int c = 1; c < NCLS; ++c) mx = fmaxf(mx, v[c]);
    float s = 0.f;
#pragma unroll
    for (int c = 0; c < NCLS; ++c) { v[c] = __expf(v[c] - mx); s += v[c]; }
    float inv = 1.0f / s;
#pragma unroll
    for (int c = 0; c < NCLS; ++c) v[c] *= inv;
}

// R9 structure (best measured: total 101.6 µs). Phase 1: 8 independent label
// gathers/thread (the irreducible 4.19M requests), TRUE survivors -> LDS via
// LDS atomic. Phase 2: one lane-dense round of row gathers + softmax + dist.
// Request-throughput-bound: R8 (2048x256) and R9 (4096x128) time identically.
// Hash pre-filters (R10/R11) regressed: filter VALU/LDS cost > gather savings.
// NT hint on ref_idx (streamed once) to keep logits resident in per-XCD L2.
__global__ __launch_bounds__(TPB) void fused_kernel(
    const float* __restrict__ logits, const int* __restrict__ labels,
    const int* __restrict__ ref_idx,
    unsigned int* __restrict__ counts, float* __restrict__ partials,
    long long total_pairs) {
    __shared__ unsigned int s_buf[PPB];   // 4 KB
    __shared__ int s_cnt;
    __shared__ float s_wsum[TPB / 64];
    const int tid = threadIdx.x;
    if (tid == 0) s_cnt = 0;
    __syncthreads();

    // ---- phase 1: scan 8 pairs (half of one point's neighborhood) ----------
    const long long pair0 = (long long)blockIdx.x * PPB + (long long)tid * 8;
    if (pair0 + 8 <= total_pairs) {
        const int p = (int)(pair0 >> 4);       // 8 | 16: all 8 pairs share one center
        const int li = labels[p];
        vint4 ra = __builtin_nontemporal_load((const vint4*)(ref_idx + pair0));
        vint4 rb = __builtin_nontemporal_load((const vint4*)(ref_idx + pair0) + 1);
        int rr[8] = {ra.x, ra.y, ra.z, ra.w, rb.x, rb.y, rb.z, rb.w};
        int nl[8];
#pragma unroll
        for (int j = 0; j < 8; ++j) nl[j] = labels[max(rr[j], 0)];  // independent gathers
        if (li != IGNORE_INDEX) {
#pragma unroll
            for (int j = 0; j < 8; ++j) {
                if (rr[j] >= 0 && nl[j] == li) {     // nl==li>=0 implies nl valid
                    int slot = atomicAdd(&s_cnt, 1); // LDS atomic: cheap
                    s_buf[slot] = ((unsigned int)(tid * 8 + j) << RBITS) |
                                  (unsigned int)rr[j];
                }
            }
        }
    }
    __syncthreads();
    const int c = s_cnt;                        // <= PPB by construction

    // ---- phase 2: lane-dense pair processing straight from LDS -------------
    float fsum = 0.f;
    for (int i = tid; i < c; i += TPB) {
        unsigned int e = s_buf[i];
        unsigned int lid = e >> RBITS;                        // local pair id [0,1024)
        unsigned int r = e & ((1u << RBITS) - 1u);            // neighbor index
        unsigned int p = (unsigned int)blockIdx.x * (PPB / 16) + (lid >> 4);
        float a[NCLS], b[NCLS];
        softmax_row(logits + (size_t)p * NCLS, a);
        softmax_row(logits + (size_t)r * NCLS, b);
        float d = 0.f;
#pragma unroll
        for (int k = 0; k < NCLS; ++k) {
            float dx = a[k] - b[k];
            d = fmaf(dx, dx, d);
        }
        fsum += d;
    }

    // ---- block reduction -> plain stores (no global atomics; R5: contended
    // same-address atomics cost ~11 ns each, serialized) ----------------------
#pragma unroll
    for (int off = 32; off > 0; off >>= 1) fsum += __shfl_down(fsum, off, 64);
    if ((tid & 63) == 0) s_wsum[tid >> 6] = fsum;
    __syncthreads();
    if (tid == 0) {
        float t = 0.f;
#pragma unroll
        for (int w = 0; w < TPB / 64; ++w) t += s_wsum[w];
        partials[blockIdx.x] = t;
        counts[blockIdx.x] = (unsigned int)c;
    }
}

// ---- final single-block reduction ------------------------------------------
__global__ __launch_bounds__(1024) void reduce_kernel(
    const float* __restrict__ partials, const unsigned int* __restrict__ counts,
    float* __restrict__ out, int m) {
    double dsum = 0.0;
    unsigned long long cnt = 0;
    for (int i = threadIdx.x; i < m; i += 1024) {
        dsum += (double)partials[i];
        // clamp: counts may be 0xAA-poisoned in an isolated rocprof replay
        cnt  += (unsigned long long)min(counts[i], (unsigned int)PPB);
    }
#pragma unroll
    for (int off = 32; off > 0; off >>= 1) {
        dsum += __shfl_down(dsum, off, 64);
        cnt  += __shfl_down(cnt,  off, 64);
    }
    __shared__ double s_sum[16];
    __shared__ unsigned long long s_cnt[16];
    const int wave = threadIdx.x >> 6;
    if ((threadIdx.x & 63) == 0) { s_sum[wave] = dsum; s_cnt[wave] = cnt; }
    __syncthreads();
    if (threadIdx.x == 0) {
        double ts = 0.0; unsigned long long tc = 0;
        for (int w = 0; w < 16; ++w) { ts += s_sum[w]; tc += s_cnt[w]; }
        if (tc < 1ull) tc = 1ull;
        out[0] = (float)(ts / (double)tc);     // LOSS_WEIGHT = 1.0
    }
}

extern "C" void kernel_launch(void* const* d_in, const int* in_sizes, int n_in,
                              void* d_out, int out_size, void* d_ws, size_t ws_size,
                              hipStream_t stream) {
    const float* seg_logits = (const float*)d_in[0];
    // d_in[1] = coord — unused (KNN indices are given)
    const int* labels  = (const int*)d_in[2];
    const int* ref_idx = (const int*)d_in[3];
    float* out = (float*)d_out;
    const int n = in_sizes[2];                       // 262144
    const long long total_pairs = (long long)n * 16; // 4,194,304

    // ws layout: counts[4096] | partials[4096]  (32 KB)
    unsigned int* counts = (unsigned int*)d_ws;
    float* partials      = (float*)((char*)d_ws + BLOCKS * 4);

    fused_kernel<<<BLOCKS, TPB, 0, stream>>>(seg_logits, labels, ref_idx,
                                             counts, partials, total_pairs);
    reduce_kernel<<<1, 1024, 0, stream>>>(partials, counts, out, BLOCKS);
}

// Round 14
// 102.382 us; speedup vs baseline: 1.2057x; 1.0251x over previous
//
#include <hip/hip_runtime.h>

#define NCLS 20
#define IGNORE_INDEX (-1)
#define TPB 128             // 2-wave blocks; 16 blocks/CU co-resident
#define PAIRS_PER_THREAD 8
#define PPB (TPB * PAIRS_PER_THREAD)   // 1024 pairs per block
#define BLOCKS 4096                    // 4,194,304 / 1024
#define RBITS 18            // n = 262144 = 2^18 -> neighbor index fits 18 bits

__device__ __forceinline__ void softmax_row(const float* __restrict__ row, float* v) {
    const float4* r4 = (const float4*)row;   // 80B rows, 16B-aligned
#pragma unroll
    for (int q = 0; q < 5; ++q) {
        float4 t = r4[q];
        v[4 * q + 0] = t.x; v[4 * q + 1] = t.y;
        v[4 * q + 2] = t.z; v[4 * q + 3] = t.w;
    }
    float mx = v[0];
#pragma unroll
    for (int c = 1; c < NCLS; ++c) mx = fmaxf(mx, v[c]);
    float s = 0.f;
#pragma unroll
    for (int c = 0; c < NCLS; ++c) { v[c] = __expf(v[c] - mx); s += v[c]; }
    float inv = 1.0f / s;
#pragma unroll
    for (int c = 0; c < NCLS; ++c) v[c] *= inv;
}

// Best-measured structure (R9: 101.6 µs total). Phase 1: 8 independent label
// gathers/thread (the irreducible 4.19M requests), true survivors -> LDS via
// LDS atomic. Phase 2: one lane-dense round of row gathers + softmax + dist.
// Request-throughput-bound (~3.4 cyc/divergent lane-request): 2048x256 and
// 4096x128 grids time identically; nt-hints neutral; hash pre-filters
// (R10/R11) regressed — filter VALU/LDS cost exceeds gather savings; global
// same-address atomics (R5) cost ~11 ns each, serialized — use plain stores.
__global__ __launch_bounds__(TPB) void fused_kernel(
    const float* __restrict__ logits, const int* __restrict__ labels,
    const int* __restrict__ ref_idx,
    unsigned int* __restrict__ counts, float* __restrict__ partials,
    long long total_pairs) {
    __shared__ unsigned int s_buf[PPB];   // 4 KB
    __shared__ int s_cnt;
    __shared__ float s_wsum[TPB / 64];
    const int tid = threadIdx.x;
    if (tid == 0) s_cnt = 0;
    __syncthreads();

    // ---- phase 1: scan 8 pairs (half of one point's neighborhood) ----------
    const long long pair0 = (long long)blockIdx.x * PPB + (long long)tid * 8;
    if (pair0 + 8 <= total_pairs) {
        const int p = (int)(pair0 >> 4);       // 8 | 16: all 8 pairs share one center
        const int li = labels[p];
        int4 ra = *(const int4*)(ref_idx + pair0);
        int4 rb = *(const int4*)(ref_idx + pair0 + 4);
        int rr[8] = {ra.x, ra.y, ra.z, ra.w, rb.x, rb.y, rb.z, rb.w};
        int nl[8];
#pragma unroll
        for (int j = 0; j < 8; ++j) nl[j] = labels[max(rr[j], 0)];  // independent gathers
        if (li != IGNORE_INDEX) {
#pragma unroll
            for (int j = 0; j < 8; ++j) {
                if (rr[j] >= 0 && nl[j] == li) {     // nl==li>=0 implies nl valid
                    int slot = atomicAdd(&s_cnt, 1); // LDS atomic: cheap
                    s_buf[slot] = ((unsigned int)(tid * 8 + j) << RBITS) |
                                  (unsigned int)rr[j];
                }
            }
        }
    }
    __syncthreads();
    const int c = s_cnt;                        // <= PPB by construction

    // ---- phase 2: lane-dense pair processing straight from LDS -------------
    float fsum = 0.f;
    for (int i = tid; i < c; i += TPB) {
        unsigned int e = s_buf[i];
        unsigned int lid = e >> RBITS;                        // local pair id [0,1024)
        unsigned int r = e & ((1u << RBITS) - 1u);            // neighbor index
        unsigned int p = (unsigned int)blockIdx.x * (PPB / 16) + (lid >> 4);
        float a[NCLS], b[NCLS];
        softmax_row(logits + (size_t)p * NCLS, a);
        softmax_row(logits + (size_t)r * NCLS, b);
        float d = 0.f;
#pragma unroll
        for (int k = 0; k < NCLS; ++k) {
            float dx = a[k] - b[k];
            d = fmaf(dx, dx, d);
        }
        fsum += d;
    }

    // ---- block reduction -> plain stores (no global atomics) ---------------
#pragma unroll
    for (int off = 32; off > 0; off >>= 1) fsum += __shfl_down(fsum, off, 64);
    if ((tid & 63) == 0) s_wsum[tid >> 6] = fsum;
    __syncthreads();
    if (tid == 0) {
        float t = 0.f;
#pragma unroll
        for (int w = 0; w < TPB / 64; ++w) t += s_wsum[w];
        partials[blockIdx.x] = t;
        counts[blockIdx.x] = (unsigned int)c;
    }
}

// ---- final single-block reduction ------------------------------------------
__global__ __launch_bounds__(1024) void reduce_kernel(
    const float* __restrict__ partials, const unsigned int* __restrict__ counts,
    float* __restrict__ out, int m) {
    double dsum = 0.0;
    unsigned long long cnt = 0;
    for (int i = threadIdx.x; i < m; i += 1024) {
        dsum += (double)partials[i];
        // clamp: counts may be 0xAA-poisoned in an isolated rocprof replay
        cnt  += (unsigned long long)min(counts[i], (unsigned int)PPB);
    }
#pragma unroll
    for (int off = 32; off > 0; off >>= 1) {
        dsum += __shfl_down(dsum, off, 64);
        cnt  += __shfl_down(cnt,  off, 64);
    }
    __shared__ double s_sum[16];
    __shared__ unsigned long long s_cnt[16];
    const int wave = threadIdx.x >> 6;
    if ((threadIdx.x & 63) == 0) { s_sum[wave] = dsum; s_cnt[wave] = cnt; }
    __syncthreads();
    if (threadIdx.x == 0) {
        double ts = 0.0; unsigned long long tc = 0;
        for (int w = 0; w < 16; ++w) { ts += s_sum[w]; tc += s_cnt[w]; }
        if (tc < 1ull) tc = 1ull;
        out[0] = (float)(ts / (double)tc);     // LOSS_WEIGHT = 1.0
    }
}

extern "C" void kernel_launch(void* const* d_in, const int* in_sizes, int n_in,
                              void* d_out, int out_size, void* d_ws, size_t ws_size,
                              hipStream_t stream) {
    const float* seg_logits = (const float*)d_in[0];
    // d_in[1] = coord — unused (KNN indices are given)
    const int* labels  = (const int*)d_in[2];
    const int* ref_idx = (const int*)d_in[3];
    float* out = (float*)d_out;
    const int n = in_sizes[2];                       // 262144
    const long long total_pairs = (long long)n * 16; // 4,194,304

    // ws layout: counts[4096] | partials[4096]  (32 KB)
    unsigned int* counts = (unsigned int*)d_ws;
    float* partials      = (float*)((char*)d_ws + BLOCKS * 4);

    fused_kernel<<<BLOCKS, TPB, 0, stream>>>(seg_logits, labels, ref_idx,
                                             counts, partials, total_pairs);
    reduce_kernel<<<1, 1024, 0, stream>>>(partials, counts, out, BLOCKS);
}